// Round 4
// baseline (108.373 us; speedup 1.0000x reference)
//
#include <hip/hip_runtime.h>

// Flat balanced table-batched embedding bags.
// weights [T*E, D=64] f32, indices [N], offsets [T*B+1] (segment s = t*B+b),
// out [B, T, D] f32 (pre-zeroed; bag partials merged with fp32 HW atomics).
//
// Decomposition: wave w owns index rows [64w, 64w+64). Lane=(r,c): slot r
// (0..3) owns 16 consecutive rows, c = float4 chunk of the D=64 row.
// Perfectly balanced: all waves do identical work regardless of bag raggedness.
// Gathers (16 dwordx4/slot, 256 B/lane in flight) depend only on idx loads +
// table-id; the per-slot binary search & segment walk overlap them.

__device__ __forceinline__ void flush_seg(float* __restrict__ out, int seg,
                                          int B, int T, int c, const float4& a) {
    if (a.x == 0.f && a.y == 0.f && a.z == 0.f && a.w == 0.f) return;
    const int t = seg / B;
    const int b = seg - t * B;
    float* p = out + (((size_t)b * T + t) << 6) + (c << 2);
    unsafeAtomicAdd(p + 0, a.x);
    unsafeAtomicAdd(p + 1, a.y);
    unsafeAtomicAdd(p + 2, a.z);
    unsafeAtomicAdd(p + 3, a.w);
}

__global__ __launch_bounds__(256) void emb_flat_kernel(
    const float* __restrict__ weights,
    const int*   __restrict__ table_offsets,
    const int*   __restrict__ indices,
    const int*   __restrict__ offsets,
    float*       __restrict__ out,
    int N, int TB, int B, int T)
{
    const int wave = (blockIdx.x * blockDim.x + threadIdx.x) >> 6;
    const int lane = threadIdx.x & 63;
    const int c = lane & 15;          // float4 chunk within a row
    const int r = lane >> 4;          // row slot 0..3

    const int p0 = (wave << 6) + (r << 4);   // slot's first row
    if (p0 >= N) return;                     // dead slot; no barriers follow
    const int pl = min(p0 + 15, N - 1);      // slot's last valid row

    // ---- table id bounds for this slot: t(p) = #{j in [1,T): offsets[j*B] <= p}
    int t_first = 0, t_last = 0;
    for (int j = 1; j < T; ++j) {
        const int bj = offsets[j * B];
        t_first += (p0 >= bj) ? 1 : 0;
        t_last  += (pl >= bj) ? 1 : 0;
    }

    // ---- 16 independent index loads (clamped; all static-indexed) ----
    int idx[16];
    #pragma unroll
    for (int k = 0; k < 16; ++k) {
        const int p = p0 + k;
        idx[k] = indices[p <= pl ? p : pl];
    }

    // ---- per-row table base (uniform fast path: boundary inside slot is ~0.05%)
    int tbase[16];
    if (t_first == t_last) {
        const int tb = table_offsets[t_first];
        #pragma unroll
        for (int k = 0; k < 16; ++k) tbase[k] = tb;
    } else {
        #pragma unroll
        for (int k = 0; k < 16; ++k) {
            int t = t_first;
            for (int j = t_first + 1; j <= t_last; ++j)
                t += ((p0 + k) >= offsets[j * B]) ? 1 : 0;
            tbase[k] = table_offsets[t];
        }
    }

    // ---- issue all 16 gathers (256 B/lane in flight) ----
    const float4* __restrict__ w4 = (const float4*)weights;
    float4 v[16];
    #pragma unroll
    for (int k = 0; k < 16; ++k) {
        if (p0 + k < N) v[k] = w4[((size_t)(tbase[k] + idx[k]) << 4) + c];
        else            v[k] = make_float4(0.f, 0.f, 0.f, 0.f);
    }

    // ---- binary search: seg = last j with offsets[j] <= p0 ----
    int lo = 0, hi = TB;                  // offsets[0]=0 <= p0 < N = offsets[TB]
    while (hi - lo > 1) {
        const int mid = (lo + hi) >> 1;
        const int om  = offsets[mid];
        lo = (om <= p0) ? mid : lo;
        hi = (om <= p0) ? hi  : mid;
    }
    int seg = lo;
    int nxt = offsets[seg + 1];

    // ---- ordered accumulate with boundary flushes ----
    float4 acc = make_float4(0.f, 0.f, 0.f, 0.f);
    #pragma unroll
    for (int k = 0; k < 16; ++k) {
        const int p = p0 + k;
        if (p < N) {
            while (p >= nxt) {            // crossed into next bag (skips empties)
                flush_seg(out, seg, B, T, c, acc);
                acc = make_float4(0.f, 0.f, 0.f, 0.f);
                ++seg;
                nxt = offsets[seg + 1];
            }
            acc.x += v[k].x; acc.y += v[k].y; acc.z += v[k].z; acc.w += v[k].w;
        }
    }
    flush_seg(out, seg, B, T, c, acc);
}

extern "C" void kernel_launch(void* const* d_in, const int* in_sizes, int n_in,
                              void* d_out, int out_size, void* d_ws, size_t ws_size,
                              hipStream_t stream) {
    const float* weights       = (const float*)d_in[0];
    const int*   table_offsets = (const int*)d_in[1];
    const int*   indices       = (const int*)d_in[2];
    const int*   offsets       = (const int*)d_in[3];
    float*       out           = (float*)d_out;

    const int T  = in_sizes[1];          // 8
    const int TB = in_sizes[3] - 1;      // T*B
    const int B  = TB / T;               // 2048
    const int N  = in_sizes[2];          // total index rows

    // output accumulated via atomics -> zero it first (async, capturable)
    hipMemsetAsync(d_out, 0, (size_t)out_size * sizeof(float), stream);

    const int waves   = (N + 63) >> 6;   // one wave per 64 rows
    const int threads = 256;
    const int blocks  = (int)(((long long)waves * 64 + threads - 1) / threads);
    emb_flat_kernel<<<blocks, threads, 0, stream>>>(
        weights, table_offsets, indices, offsets, out, N, TB, B, T);
}

// Round 5
// 38.394 us; speedup vs baseline: 2.8226x; 2.8226x over previous
//
#include <hip/hip_runtime.h>

// Table-batched embedding bags: weights [T*E, D=64] f32, indices [N] local,
// offsets [T*B+1] ragged bags (segment s = t*B + b), out [B, T, D] f32.
//
// One wave per bag (R2 structure). Lane=(r,c): r=lane>>4 row-slot, c=lane&15
// float4 chunk. NEW vs R2: indices are loaded ONCE per 64 rows with a single
// coalesced VMEM inst (indices[i+lane]) and distributed to slots via __shfl
// (ds_bpermute, no memory traffic) -- cuts VMEM instruction / line-lookup
// count ~2x on the index side. Gathers: 8 independent dwordx4 per lane per
// 32-row half (128 B/lane in flight), invalid rows exec-masked (no request).

__global__ __launch_bounds__(256) void emb_bags_kernel(
    const float* __restrict__ weights,
    const int*   __restrict__ table_offsets,
    const int*   __restrict__ indices,
    const int*   __restrict__ offsets,
    float*       __restrict__ out,
    int TB, int B, int T)
{
    const int wave = (blockIdx.x * blockDim.x + threadIdx.x) >> 6;
    if (wave >= TB) return;
    const int lane = threadIdx.x & 63;
    const int c = lane & 15;   // float4 chunk within row
    const int r = lane >> 4;   // row slot 0..3

    const int t = wave / B;
    const int b = wave - t * B;
    const int start = offsets[wave];
    const int end   = offsets[wave + 1];
    const long long tbase = table_offsets[t];

    const float4* __restrict__ w4 = (const float4*)weights;

    float4 a0 = make_float4(0.f, 0.f, 0.f, 0.f);
    float4 a1 = a0;

    for (int i = start; i < end; i += 64) {
        const int e1 = end - 1;
        const int p  = i + lane;
        const int myidx = indices[p <= e1 ? p : e1];   // 1 coalesced VMEM / 64 rows

        #pragma unroll
        for (int h = 0; h < 2; ++h) {                  // two 32-row halves
            const int base = i + (h << 5) + (r << 3);  // this slot's 8 rows
            // distribute indices in-register; then 8 independent gathers
            int id[8];
            #pragma unroll
            for (int k = 0; k < 8; ++k)
                id[k] = __shfl(myidx, (h << 5) + (r << 3) + k, 64);

            float4 v[8];
            #pragma unroll
            for (int k = 0; k < 8; ++k) {
                if (base + k < end)
                    v[k] = w4[((size_t)(tbase + id[k]) << 4) + c];
                else
                    v[k] = make_float4(0.f, 0.f, 0.f, 0.f);
            }

            #pragma unroll
            for (int k = 0; k < 8; k += 2) {
                a0.x += v[k].x;     a0.y += v[k].y;
                a0.z += v[k].z;     a0.w += v[k].w;
                a1.x += v[k + 1].x; a1.y += v[k + 1].y;
                a1.z += v[k + 1].z; a1.w += v[k + 1].w;
            }
        }
    }

    float4 a;
    a.x = a0.x + a1.x;
    a.y = a0.y + a1.y;
    a.z = a0.z + a1.z;
    a.w = a0.w + a1.w;

    // reduce across the 4 row-slots (lane bits 4 and 5)
    #pragma unroll
    for (int m = 16; m < 64; m <<= 1) {
        a.x += __shfl_xor(a.x, m, 64);
        a.y += __shfl_xor(a.y, m, 64);
        a.z += __shfl_xor(a.z, m, 64);
        a.w += __shfl_xor(a.w, m, 64);
    }

    if (r == 0) {
        float4* o4 = (float4*)out;
        o4[(((size_t)b * T + t) << 4) + c] = a;  // out[b, t, c*4 .. c*4+3]
    }
}

extern "C" void kernel_launch(void* const* d_in, const int* in_sizes, int n_in,
                              void* d_out, int out_size, void* d_ws, size_t ws_size,
                              hipStream_t stream) {
    const float* weights       = (const float*)d_in[0];
    const int*   table_offsets = (const int*)d_in[1];
    const int*   indices       = (const int*)d_in[2];
    const int*   offsets       = (const int*)d_in[3];
    float*       out           = (float*)d_out;

    const int T  = in_sizes[1];          // 8
    const int TB = in_sizes[3] - 1;      // T*B
    const int B  = TB / T;               // 2048

    const int threads = 256;             // 4 waves/block
    const int blocks  = (TB * 64 + threads - 1) / threads;
    emb_bags_kernel<<<blocks, threads, 0, stream>>>(
        weights, table_offsets, indices, offsets, out, TB, B, T);
}